// Round 1
// baseline (984.261 us; speedup 1.0000x reference)
//
#include <hip/hip_runtime.h>
#include <hip/hip_bf16.h>

#define H_ 16
#define B_ 8
#define S_ 1024
#define D_ 1024
#define E_ 64
#define HB_ 128
#define LN_EPS 1e-5f

typedef unsigned short u16;
typedef __bf16 bf16x8 __attribute__((ext_vector_type(8)));
typedef u16 u16x8 __attribute__((ext_vector_type(8)));
typedef float f32x4 __attribute__((ext_vector_type(4)));

#define MFMA16(a, b, c) __builtin_amdgcn_mfma_f32_16x16x32_bf16( \
    __builtin_bit_cast(bf16x8, (a)), __builtin_bit_cast(bf16x8, (b)), (c), 0, 0, 0)

__device__ __forceinline__ u16 f2bf(float x) {
  union { float f; unsigned u; } v; v.f = x;
  unsigned r = v.u + 0x7fffu + ((v.u >> 16) & 1u);
  return (u16)(r >> 16);
}

// ---- prep: W [H][D][E] f32 -> Wt [(h*64+e)][D] bf16 (scaled) ----
__global__ void k_transpose_w(const float* __restrict__ W, u16* __restrict__ Wt, float scale) {
  int tid = blockIdx.x * 256 + threadIdx.x;   // H*D*E = 1,048,576
  int e = tid & 63, d = (tid >> 6) & 1023, h = tid >> 16;
  Wt[(size_t)(h * 64 + e) * 1024 + d] = f2bf(W[tid] * scale);
}

// ---- prep: Wp [K][N] f32 -> Wpt [N][K] bf16 ----
__global__ void k_transpose_wp(const float* __restrict__ W, u16* __restrict__ Wt) {
  int tid = blockIdx.x * 256 + threadIdx.x;   // 1,048,576
  int n = tid & 1023, k = tid >> 10;
  Wt[(size_t)n * 1024 + k] = f2bf(W[tid]);
}

// ---- QKV projection GEMM: X[8192][1024] f32 @ Wt[(h*64+e)][k] bf16 ----
// transposed==0: out[hb][s][e] bf16   (Q, K)
// transposed==1: out[hb][e][s] bf16   (V^T)
__global__ __launch_bounds__(256) void k_qkv_gemm(const float* __restrict__ X,
    const u16* __restrict__ Wt, u16* __restrict__ out, int transposed) {
  const int mt = blockIdx.x;        // 64 m-tiles of 128 rows
  const int h  = blockIdx.y;        // 16 heads = 64-wide n-tile
  const int w  = threadIdx.x >> 6;
  const int l  = threadIdx.x & 63;
  const int lr = l & 15, lg = l >> 4;
  const int m0 = mt * 128 + w * 32;

  f32x4 acc[2][4] = {};
  const float* Xp = X + (size_t)(m0 + lr) * 1024 + lg * 8;
  const u16*  Bp0 = Wt + (size_t)(h * 64 + lr) * 1024 + lg * 8;

  for (int k = 0; k < 1024; k += 32) {
    u16x8 a[2];
    #pragma unroll
    for (int i = 0; i < 2; i++) {
      const float* p = Xp + (size_t)i * 16 * 1024 + k;
      float4 x0 = *(const float4*)p;
      float4 x1 = *(const float4*)(p + 4);
      u16x8 t;
      t[0] = f2bf(x0.x); t[1] = f2bf(x0.y); t[2] = f2bf(x0.z); t[3] = f2bf(x0.w);
      t[4] = f2bf(x1.x); t[5] = f2bf(x1.y); t[6] = f2bf(x1.z); t[7] = f2bf(x1.w);
      a[i] = t;
    }
    #pragma unroll
    for (int j = 0; j < 4; j++) {
      u16x8 b = *(const u16x8*)(Bp0 + (size_t)j * 16 * 1024 + k);
      #pragma unroll
      for (int i = 0; i < 2; i++)
        acc[i][j] = MFMA16(a[i], b, acc[i][j]);
    }
  }

  #pragma unroll
  for (int i = 0; i < 2; i++)
    #pragma unroll
    for (int j = 0; j < 4; j++)
      #pragma unroll
      for (int r = 0; r < 4; r++) {
        int m = m0 + i * 16 + lg * 4 + r;
        int bb = m >> 10, s = m & 1023;
        int e = j * 16 + lr;
        u16 v = f2bf(acc[i][j][r]);
        if (!transposed)
          out[((size_t)(h * 8 + bb) * 1024 + s) * 64 + e] = v;
        else
          out[((size_t)(h * 8 + bb) * 64 + e) * 1024 + s] = v;
      }
}

// ---- attention: per wg = (hb, 16 q rows); 4 waves split Sk into 256-col slices ----
__global__ __launch_bounds__(256) void k_attn(const u16* __restrict__ Qb,
    const u16* __restrict__ Kb, const u16* __restrict__ Vtb,
    float* __restrict__ attn_out, u16* __restrict__ AO) {
  const int qt = blockIdx.x;        // 64 q-tiles
  const int hb = blockIdx.y;        // 128
  const int w  = threadIdx.x >> 6;
  const int l  = threadIdx.x & 63;
  const int lr = l & 15, lg = l >> 4;
  const int q0 = qt * 16;

  __shared__ __align__(16) u16 pbuf[16][1032];   // +8 pad kills bank conflicts
  __shared__ float red_m[4][16];
  __shared__ float red_s[4][16];
  __shared__ float obuf[4][16][64];

  // --- QK^T (Q pre-scaled by 1/32) ---
  const u16* Qp = Qb + ((size_t)hb * 1024 + q0 + lr) * 64 + lg * 8;
  const u16* Kp = Kb + ((size_t)hb * 1024 + w * 256 + lr) * 64 + lg * 8;
  u16x8 a0 = *(const u16x8*)Qp;
  u16x8 a1 = *(const u16x8*)(Qp + 32);

  f32x4 sacc[16] = {};
  #pragma unroll
  for (int j = 0; j < 16; j++) {
    u16x8 b0 = *(const u16x8*)(Kp + (size_t)j * 16 * 64);
    u16x8 b1 = *(const u16x8*)(Kp + (size_t)j * 16 * 64 + 32);
    sacc[j] = MFMA16(a0, b0, sacc[j]);
    sacc[j] = MFMA16(a1, b1, sacc[j]);
  }

  // --- softmax: row max ---
  float rowm[4];
  #pragma unroll
  for (int r = 0; r < 4; r++) {
    float m = sacc[0][r];
    #pragma unroll
    for (int j = 1; j < 16; j++) m = fmaxf(m, sacc[j][r]);
    #pragma unroll
    for (int off = 1; off < 16; off <<= 1) m = fmaxf(m, __shfl_xor(m, off));
    rowm[r] = m;
  }
  if (lr == 0) {
    #pragma unroll
    for (int r = 0; r < 4; r++) red_m[w][lg * 4 + r] = rowm[r];
  }
  __syncthreads();
  #pragma unroll
  for (int r = 0; r < 4; r++) {
    int row = lg * 4 + r;
    rowm[r] = fmaxf(fmaxf(red_m[0][row], red_m[1][row]),
                    fmaxf(red_m[2][row], red_m[3][row]));
  }

  // --- exp + row sum ---
  float rsum[4];
  #pragma unroll
  for (int r = 0; r < 4; r++) {
    float s = 0.f;
    #pragma unroll
    for (int j = 0; j < 16; j++) {
      float p = __expf(sacc[j][r] - rowm[r]);
      sacc[j][r] = p;
      s += p;
    }
    #pragma unroll
    for (int off = 1; off < 16; off <<= 1) s += __shfl_xor(s, off);
    rsum[r] = s;
  }
  if (lr == 0) {
    #pragma unroll
    for (int r = 0; r < 4; r++) red_s[w][lg * 4 + r] = rsum[r];
  }
  __syncthreads();
  float inv[4];
  #pragma unroll
  for (int r = 0; r < 4; r++) {
    int row = lg * 4 + r;
    inv[r] = 1.0f / (red_s[0][row] + red_s[1][row] + red_s[2][row] + red_s[3][row]);
  }

  // --- write attn (f32, output) + pbuf (bf16 for PV) ---
  #pragma unroll
  for (int j = 0; j < 16; j++)
    #pragma unroll
    for (int r = 0; r < 4; r++) {
      int row = lg * 4 + r;
      int col = w * 256 + j * 16 + lr;
      float p = sacc[j][r] * inv[r];
      attn_out[((size_t)hb * 1024 + q0 + row) * 1024 + col] = p;
      pbuf[row][col] = f2bf(p);
    }

  // --- PV: each wave accumulates over its own 256-col k-slice (reads only what it wrote) ---
  f32x4 oacc[4] = {};
  const u16* Vp = Vtb + ((size_t)hb * 64 + lr) * 1024 + w * 256 + lg * 8;
  #pragma unroll
  for (int kk = 0; kk < 8; kk++) {
    u16x8 a = *(const u16x8*)&pbuf[lr][w * 256 + kk * 32 + lg * 8];
    #pragma unroll
    for (int j = 0; j < 4; j++) {
      u16x8 b = *(const u16x8*)(Vp + (size_t)j * 16 * 1024 + kk * 32);
      oacc[j] = MFMA16(a, b, oacc[j]);
    }
  }
  #pragma unroll
  for (int j = 0; j < 4; j++)
    #pragma unroll
    for (int r = 0; r < 4; r++)
      obuf[w][lg * 4 + r][j * 16 + lr] = oacc[j][r];
  __syncthreads();

  // --- cross-wave reduce + write attout bf16 [b][s][h*64+e] ---
  const int bb = hb & 7, hh = hb >> 3;
  #pragma unroll
  for (int ii = 0; ii < 4; ii++) {
    int idx = ii * 256 + threadIdx.x;
    int row = idx >> 6, col = idx & 63;
    float s = obuf[0][row][col] + obuf[1][row][col] + obuf[2][row][col] + obuf[3][row][col];
    AO[((size_t)bb * 1024 + q0 + row) * 1024 + hh * 64 + col] = f2bf(s);
  }
}

// ---- projection + bias + residual + LayerNorm ----
__global__ __launch_bounds__(512) void k_proj_ln(const u16* __restrict__ AO,
    const u16* __restrict__ Wpt, const float* __restrict__ bp,
    const float* __restrict__ query, const float* __restrict__ gamma,
    const float* __restrict__ beta, float* __restrict__ y) {
  const int w  = threadIdx.x >> 6;
  const int l  = threadIdx.x & 63;
  const int lr = l & 15, lg = l >> 4;
  const int wm = w >> 2, wn = w & 3;
  const int m0 = blockIdx.x * 32 + wm * 16;
  const int n0 = wn * 256;

  __shared__ float reds1[4][2][16];
  __shared__ float reds2[4][2][16];

  f32x4 acc[16] = {};
  const u16* Ap = AO + (size_t)(m0 + lr) * 1024 + lg * 8;
  const u16* Bp = Wpt + (size_t)(n0 + lr) * 1024 + lg * 8;

  for (int k = 0; k < 1024; k += 32) {
    u16x8 a = *(const u16x8*)(Ap + k);
    #pragma unroll
    for (int j = 0; j < 16; j++) {
      u16x8 b = *(const u16x8*)(Bp + (size_t)j * 16 * 1024 + k);
      acc[j] = MFMA16(a, b, acc[j]);
    }
  }

  // epilogue: + bias + residual
  #pragma unroll
  for (int j = 0; j < 16; j++)
    #pragma unroll
    for (int r = 0; r < 4; r++) {
      int m = m0 + lg * 4 + r;
      int col = n0 + j * 16 + lr;
      acc[j][r] += bp[col] + query[(size_t)m * 1024 + col];
    }

  // LN stats
  float s1[4], s2[4];
  #pragma unroll
  for (int r = 0; r < 4; r++) {
    float s = 0.f, q = 0.f;
    #pragma unroll
    for (int j = 0; j < 16; j++) { float v = acc[j][r]; s += v; q += v * v; }
    #pragma unroll
    for (int off = 1; off < 16; off <<= 1) { s += __shfl_xor(s, off); q += __shfl_xor(q, off); }
    s1[r] = s; s2[r] = q;
  }
  if (lr == 0) {
    #pragma unroll
    for (int r = 0; r < 4; r++) {
      reds1[wn][wm][lg * 4 + r] = s1[r];
      reds2[wn][wm][lg * 4 + r] = s2[r];
    }
  }
  __syncthreads();
  #pragma unroll
  for (int r = 0; r < 4; r++) {
    int row = lg * 4 + r;
    float S1 = reds1[0][wm][row] + reds1[1][wm][row] + reds1[2][wm][row] + reds1[3][wm][row];
    float S2 = reds2[0][wm][row] + reds2[1][wm][row] + reds2[2][wm][row] + reds2[3][wm][row];
    float mu = S1 * (1.0f / 1024.0f);
    float var = S2 * (1.0f / 1024.0f) - mu * mu;
    float rstd = rsqrtf(var + LN_EPS);
    int m = m0 + lg * 4 + r;
    #pragma unroll
    for (int j = 0; j < 16; j++) {
      int col = n0 + j * 16 + lr;
      y[(size_t)m * 1024 + col] = (acc[j][r] - mu) * rstd * gamma[col] + beta[col];
    }
  }
}

extern "C" void kernel_launch(void* const* d_in, const int* in_sizes, int n_in,
                              void* d_out, int out_size, void* d_ws, size_t ws_size,
                              hipStream_t stream) {
  const float* query  = (const float*)d_in[0];
  const float* keys   = (const float*)d_in[1];
  const float* values = (const float*)d_in[2];
  const float* Wq     = (const float*)d_in[3];
  const float* Wk     = (const float*)d_in[4];
  const float* Wv     = (const float*)d_in[5];
  const float* Wp     = (const float*)d_in[6];
  const float* bp     = (const float*)d_in[7];
  const float* gamma  = (const float*)d_in[8];
  const float* beta   = (const float*)d_in[9];

  float* y        = (float*)d_out;                         // [8,1024,1024]
  float* attn_out = (float*)d_out + (size_t)B_ * S_ * D_;  // [128,1024,1024]

  u16* ws  = (u16*)d_ws;
  u16* Wqt = ws;                   // 1M elems each
  u16* Wkt = Wqt + (1 << 20);
  u16* Wvt = Wkt + (1 << 20);
  u16* Wpt = Wvt + (1 << 20);
  u16* Qb  = Wpt + (1 << 20);      // 128*1024*64 = 8,388,608 each
  u16* Kb  = Qb + (8 << 20);
  u16* Vtb = Kb + (8 << 20);
  u16* AO  = Vtb + (8 << 20);      // 8192*1024

  k_transpose_w<<<4096, 256, 0, stream>>>(Wq, Wqt, 1.0f / 32.0f);  // fold 1/sqrt(1024)
  k_transpose_w<<<4096, 256, 0, stream>>>(Wk, Wkt, 1.0f);
  k_transpose_w<<<4096, 256, 0, stream>>>(Wv, Wvt, 1.0f);
  k_transpose_wp<<<4096, 256, 0, stream>>>(Wp, Wpt);

  k_qkv_gemm<<<dim3(64, 16), 256, 0, stream>>>(query,  Wqt, Qb,  0);
  k_qkv_gemm<<<dim3(64, 16), 256, 0, stream>>>(keys,   Wkt, Kb,  0);
  k_qkv_gemm<<<dim3(64, 16), 256, 0, stream>>>(values, Wvt, Vtb, 1);

  k_attn<<<dim3(64, 128), 256, 0, stream>>>(Qb, Kb, Vtb, attn_out, AO);

  k_proj_ln<<<256, 512, 0, stream>>>(AO, Wpt, bp, query, gamma, beta, y);
}